// Round 8
// baseline (270.836 us; speedup 1.0000x reference)
//
#include <hip/hip_runtime.h>

// Fused GRU (Keras reset_after=True, relu) for MI355X — round 8.
// r7 structure (validated: 242 µs), single change: the rec dot uses packed
// f32x2 FMAs (v_pk_fma_f32) with U stored as k-pair f32x2 (96 pk-FMA vs
// 192 scalar FMA per step). h broadcast still via v_readlane.
// Block = 256 thr (4 waves) = 2 batch rows. Grid = 256 = 1 block/CU, one pass.
//   Wave 0/1: recurrence for row 0/1 — register-only steps, no LDS/barrier
//             inside a step; U f32x2-resident (192 VGPR).
//   Wave 2/3: x-proj producers (6 gate col-tiles each, both rows), bf16x3
//             MFMA, W frags register-resident, double-buffered Xb.
// ONE __syncthreads per 16-step chunk.

#define B_SZ   512
#define T_SZ   512
#define F_SZ   128
#define UN     64
#define G3     192
#define CHUNK  16
#define NCHUNK (T_SZ / CHUNK)
#define NCLS   10
#define GP     196   // padded gate row (floats)

using short8 = __attribute__((ext_vector_type(8))) short;
using f32x4  = __attribute__((ext_vector_type(4))) float;
using f32x2  = __attribute__((ext_vector_type(2))) float;
typedef unsigned int u32;

union S8 { short8 s; u32 u[4]; };

__device__ __forceinline__ u32 permb(u32 a, u32 b, u32 sel) {
    return __builtin_amdgcn_perm(a, b, sel);
}
__device__ __forceinline__ unsigned short f2bf_rn(float f) {
    u32 u = __float_as_uint(f);
    u32 r = u + 0x7FFFu + ((u >> 16) & 1u);
    return (unsigned short)(r >> 16);
}
__device__ __forceinline__ float bf2f(unsigned short s) {
    return __uint_as_float(((u32)s) << 16);
}
__device__ __forceinline__ float sigmoidf_(float x) {
    return 1.0f / (1.0f + __expf(-x));
}
__device__ __forceinline__ void split_pair(float f0, float f1, u32 &hi, u32 &lo) {
    u32 u0 = __float_as_uint(f0) & 0xffff0000u;
    u32 u1 = __float_as_uint(f1) & 0xffff0000u;
    float l0 = f0 - __uint_as_float(u0);
    float l1 = f1 - __uint_as_float(u1);
    hi = permb(u1, u0, 0x07060302u);
    lo = permb(__float_as_uint(l1), __float_as_uint(l0), 0x07060302u);
}
__device__ __forceinline__ float rdlane(float v, int l) {
    return __uint_as_float(__builtin_amdgcn_readlane(__float_as_uint(v), l));
}
__device__ __forceinline__ f32x2 fma2(f32x2 a, f32x2 b, f32x2 c) {
#if __has_builtin(__builtin_elementwise_fma)
    return __builtin_elementwise_fma(a, b, c);   // -> v_pk_fma_f32
#else
    f32x2 r; r[0] = fmaf(a[0], b[0], c[0]); r[1] = fmaf(a[1], b[1], c[1]); return r;
#endif
}
#define WAVE_SYNC() asm volatile("s_waitcnt lgkmcnt(0)" ::: "memory")
#define MFMA16(A, B, C) __builtin_amdgcn_mfma_f32_16x16x32_bf16((A), (B), (C), 0, 0, 0)

__global__ __launch_bounds__(256, 1)
void gru_fused8(const float* __restrict__ inp,   // [512,512,128]
                const float* __restrict__ W,     // [128,192]
                const float* __restrict__ U,     // [64,192]
                const float* __restrict__ bias,  // [2,192]
                const float* __restrict__ W1,    // [64,64]
                const float* __restrict__ b1,    // [64]
                const float* __restrict__ W2,    // [64,10]
                const float* __restrict__ b2,    // [10]
                float* __restrict__ out)         // [512,10]
{
    const int tid  = threadIdx.x;
    const int wv   = tid >> 6;
    const int lane = tid & 63;
    const int l15  = lane & 15;
    const int l4   = lane >> 4;
    const int r0   = blockIdx.x * 2;

    __shared__ __align__(16) float Xb[2][2][CHUNK][GP];   // [buf][row][t][192]
    __shared__ float hb[2][UN];
    __shared__ float sc[2][UN];
    __shared__ float lg[2][NCLS];

    if (wv >= 2) {
        // ======================= producers =======================
        const int tb = 6 * (wv - 2);      // tile base: 0 or 6
        short8 Wh[6][4], Wl[6][4];
        float  b0c[6];
        #pragma unroll
        for (int nt = 0; nt < 6; ++nt) {
            const int col = 16 * (tb + nt) + l15;
            b0c[nt] = bias[col];
            #pragma unroll
            for (int kt = 0; kt < 4; ++kt) {
                #pragma unroll
                for (int e = 0; e < 8; ++e) {
                    float w = W[(size_t)(32 * kt + 8 * l4 + e) * G3 + col];
                    unsigned short hi = f2bf_rn(w);
                    Wh[nt][kt][e] = (short)hi;
                    Wl[nt][kt][e] = (short)f2bf_rn(w - bf2f(hi));
                }
            }
        }

        auto produce = [&](int cn) {
            const int bn = cn & 1;
            #pragma unroll
            for (int r = 0; r < 2; ++r) {
                const float* ap = inp + (size_t)(r0 + r) * T_SZ * F_SZ
                                + (size_t)(cn * CHUNK + l15) * F_SZ + 8 * l4;
                f32x4 acc[6];
                #pragma unroll
                for (int nt = 0; nt < 6; ++nt) acc[nt] = (f32x4){0.f, 0.f, 0.f, 0.f};
                #pragma unroll
                for (int kt = 0; kt < 4; ++kt) {
                    f32x4 v0 = *(const f32x4*)(ap + 32 * kt);
                    f32x4 v1 = *(const f32x4*)(ap + 32 * kt + 4);
                    S8 Ah, Al;
                    split_pair(v0[0], v0[1], Ah.u[0], Al.u[0]);
                    split_pair(v0[2], v0[3], Ah.u[1], Al.u[1]);
                    split_pair(v1[0], v1[1], Ah.u[2], Al.u[2]);
                    split_pair(v1[2], v1[3], Ah.u[3], Al.u[3]);
                    #pragma unroll
                    for (int nt = 0; nt < 6; ++nt) {
                        acc[nt] = MFMA16(Ah.s, Wh[nt][kt], acc[nt]);
                        acc[nt] = MFMA16(Al.s, Wh[nt][kt], acc[nt]);
                        acc[nt] = MFMA16(Ah.s, Wl[nt][kt], acc[nt]);
                    }
                }
                #pragma unroll
                for (int nt = 0; nt < 6; ++nt) {
                    const int col = 16 * (tb + nt) + l15;
                    #pragma unroll
                    for (int q = 0; q < 4; ++q)
                        Xb[bn][r][4 * l4 + q][col] = acc[nt][q] + b0c[nt];
                }
            }
        };

        produce(0);
        __syncthreads();
        for (int c = 0; c < NCHUNK; ++c) {
            if (c + 1 < NCHUNK) produce(c + 1);
            __syncthreads();
        }
    } else {
        // ======================= recurrence (row = wv) =======================
        // U as k-pair f32x2: uz2[p] = (U[2p][g], U[2p+1][g]) for gate col g
        f32x2 uz2[32], ur2[32], uh2[32];
        #pragma unroll
        for (int p = 0; p < 32; ++p) {
            uz2[p] = (f32x2){U[(size_t)(2 * p) * G3 + lane],
                             U[(size_t)(2 * p + 1) * G3 + lane]};
            ur2[p] = (f32x2){U[(size_t)(2 * p) * G3 + 64 + lane],
                             U[(size_t)(2 * p + 1) * G3 + 64 + lane]};
            uh2[p] = (f32x2){U[(size_t)(2 * p) * G3 + 128 + lane],
                             U[(size_t)(2 * p + 1) * G3 + 128 + lane]};
        }
        const float brz = bias[G3 + lane];
        const float brr = bias[G3 + 64 + lane];
        const float brh = bias[G3 + 128 + lane];
        float h = 0.f;

        __syncthreads();

        for (int c = 0; c < NCHUNK; ++c) {
            const int buf = c & 1;
            #pragma unroll 2
            for (int s = 0; s < CHUNK; ++s) {
                const float xz = Xb[buf][wv][s][lane];
                const float xr = Xb[buf][wv][s][64 + lane];
                const float xh = Xb[buf][wv][s][128 + lane];

                f32x2 az = (f32x2){0.f, 0.f}, ar2a = az, ah2a = az;
                #pragma unroll
                for (int p = 0; p < 32; ++p) {
                    f32x2 hp;
                    hp[0] = rdlane(h, 2 * p);
                    hp[1] = rdlane(h, 2 * p + 1);
                    az   = fma2(hp, uz2[p], az);
                    ar2a = fma2(hp, ur2[p], ar2a);
                    ah2a = fma2(hp, uh2[p], ah2a);
                }
                const float rz = az[0] + az[1] + brz;
                const float rr = ar2a[0] + ar2a[1] + brr;
                const float rh = ah2a[0] + ah2a[1] + brh;
                const float z  = sigmoidf_(xz + rz);
                const float rg = sigmoidf_(xr + rr);
                const float hh = fmaxf(fmaf(rg, rh, xh), 0.f);
                h = fmaf(z, h - hh, hh);
            }
            __syncthreads();
        }

        // ---------------- epilogue: head + softmax (own row) ----------------
        hb[wv][lane] = h;
        WAVE_SYNC();

        float a = b1[lane];
        #pragma unroll 8
        for (int k = 0; k < UN; ++k)
            a = fmaf(hb[wv][k], W1[k * UN + lane], a);
        sc[wv][lane] = fmaxf(a, 0.f);
        WAVE_SYNC();

        if (lane < NCLS) {
            float acc = b2[lane];
            #pragma unroll 8
            for (int k = 0; k < UN; ++k)
                acc = fmaf(sc[wv][k], W2[k * NCLS + lane], acc);
            lg[wv][lane] = acc;
        }
        WAVE_SYNC();
        if (lane < NCLS) {
            float m = lg[wv][0];
            #pragma unroll
            for (int k = 1; k < NCLS; ++k) m = fmaxf(m, lg[wv][k]);
            float ss = 0.f;
            #pragma unroll
            for (int k = 0; k < NCLS; ++k) ss += __expf(lg[wv][k] - m);
            out[(r0 + wv) * NCLS + lane] = __expf(lg[wv][lane] - m) / ss;
        }
    }
}

extern "C" void kernel_launch(void* const* d_in, const int* in_sizes, int n_in,
                              void* d_out, int out_size, void* d_ws, size_t ws_size,
                              hipStream_t stream) {
    const float* inp  = (const float*)d_in[0];
    const float* W    = (const float*)d_in[1];
    const float* U    = (const float*)d_in[2];
    const float* bias = (const float*)d_in[3];
    const float* W1   = (const float*)d_in[4];
    const float* b1   = (const float*)d_in[5];
    const float* W2   = (const float*)d_in[6];
    const float* b2   = (const float*)d_in[7];
    float* out = (float*)d_out;

    gru_fused8<<<B_SZ / 2, 256, 0, stream>>>(inp, W, U, bias, W1, b1, W2, b2, out);
}

// Round 9
// 237.064 us; speedup vs baseline: 1.1425x; 1.1425x over previous
//
#include <hip/hip_runtime.h>

// Fused GRU (Keras reset_after=True, relu) for MI355X — round 9.
// r7 structure (242 µs validated); change: rec dot uses v_dot2_f32_f16
// (96 dot2/step vs 192 fmac), h broadcast as packed f16 pairs (32 rdlane
// vs 64). h STATE stays f32 (quantization only on matvec input).
// Block = 256 thr (4 waves) = 2 batch rows. Grid = 256, one pass.
//   Wave 0/1: recurrence row 0/1 — register-only step, U f16-packed resident.
//   Wave 2/3: x-proj producers (bf16x3 MFMA, W frags resident, dbuf Xb).
// ONE __syncthreads per 16-step chunk.

#define B_SZ   512
#define T_SZ   512
#define F_SZ   128
#define UN     64
#define G3     192
#define CHUNK  16
#define NCHUNK (T_SZ / CHUNK)
#define NCLS   10
#define GP     196

using short8 = __attribute__((ext_vector_type(8))) short;
using f32x4  = __attribute__((ext_vector_type(4))) float;
using h2     = __attribute__((ext_vector_type(2))) __fp16;
typedef unsigned int u32;

union S8 { short8 s; u32 u[4]; };
union HU { h2 h; u32 u; };

__device__ __forceinline__ u32 permb(u32 a, u32 b, u32 sel) {
    return __builtin_amdgcn_perm(a, b, sel);
}
__device__ __forceinline__ unsigned short f2bf_rn(float f) {
    u32 u = __float_as_uint(f);
    u32 r = u + 0x7FFFu + ((u >> 16) & 1u);
    return (unsigned short)(r >> 16);
}
__device__ __forceinline__ float bf2f(unsigned short s) {
    return __uint_as_float(((u32)s) << 16);
}
__device__ __forceinline__ float sigmoidf_(float x) {
    return 1.0f / (1.0f + __expf(-x));
}
__device__ __forceinline__ void split_pair(float f0, float f1, u32 &hi, u32 &lo) {
    u32 u0 = __float_as_uint(f0) & 0xffff0000u;
    u32 u1 = __float_as_uint(f1) & 0xffff0000u;
    float l0 = f0 - __uint_as_float(u0);
    float l1 = f1 - __uint_as_float(u1);
    hi = permb(u1, u0, 0x07060302u);
    lo = permb(__float_as_uint(l1), __float_as_uint(l0), 0x07060302u);
}
__device__ __forceinline__ u32 f16bits(float f) {
    __fp16 x = (__fp16)f;
    return (u32)__builtin_bit_cast(unsigned short, x);
}
__device__ __forceinline__ u32 packf16(float f0, float f1) {
    return f16bits(f0) | (f16bits(f1) << 16);
}
__device__ __forceinline__ float dot2acc(u32 hp, u32 up, float acc) {
#if __has_builtin(__builtin_amdgcn_fdot2)
    HU a, b; a.u = hp; b.u = up;
    return __builtin_amdgcn_fdot2(a.h, b.h, acc, false);
#else
    HU a, b; a.u = hp; b.u = up;
    acc = fmaf((float)a.h[0], (float)b.h[0], acc);
    return fmaf((float)a.h[1], (float)b.h[1], acc);
#endif
}
#define WAVE_SYNC() asm volatile("s_waitcnt lgkmcnt(0)" ::: "memory")
#define MFMA16(A, B, C) __builtin_amdgcn_mfma_f32_16x16x32_bf16((A), (B), (C), 0, 0, 0)

__global__ __launch_bounds__(256, 1)
void gru_fused9(const float* __restrict__ inp,   // [512,512,128]
                const float* __restrict__ W,     // [128,192]
                const float* __restrict__ U,     // [64,192]
                const float* __restrict__ bias,  // [2,192]
                const float* __restrict__ W1,    // [64,64]
                const float* __restrict__ b1,    // [64]
                const float* __restrict__ W2,    // [64,10]
                const float* __restrict__ b2,    // [10]
                float* __restrict__ out)         // [512,10]
{
    const int tid  = threadIdx.x;
    const int wv   = tid >> 6;
    const int lane = tid & 63;
    const int l15  = lane & 15;
    const int l4   = lane >> 4;
    const int r0   = blockIdx.x * 2;

    __shared__ __align__(16) float Xb[2][2][CHUNK][GP];
    __shared__ float hb[2][UN];
    __shared__ float sc[2][UN];
    __shared__ float lg[2][NCLS];

    if (wv >= 2) {
        // ======================= producers (r7-identical) =======================
        const int tb = 6 * (wv - 2);
        short8 Wh[6][4], Wl[6][4];
        float  b0c[6];
        #pragma unroll
        for (int nt = 0; nt < 6; ++nt) {
            const int col = 16 * (tb + nt) + l15;
            b0c[nt] = bias[col];
            #pragma unroll
            for (int kt = 0; kt < 4; ++kt) {
                #pragma unroll
                for (int e = 0; e < 8; ++e) {
                    float w = W[(size_t)(32 * kt + 8 * l4 + e) * G3 + col];
                    unsigned short hi = f2bf_rn(w);
                    Wh[nt][kt][e] = (short)hi;
                    Wl[nt][kt][e] = (short)f2bf_rn(w - bf2f(hi));
                }
            }
        }

        auto produce = [&](int cn) {
            const int bn = cn & 1;
            #pragma unroll
            for (int r = 0; r < 2; ++r) {
                const float* ap = inp + (size_t)(r0 + r) * T_SZ * F_SZ
                                + (size_t)(cn * CHUNK + l15) * F_SZ + 8 * l4;
                f32x4 acc[6];
                #pragma unroll
                for (int nt = 0; nt < 6; ++nt) acc[nt] = (f32x4){0.f, 0.f, 0.f, 0.f};
                #pragma unroll
                for (int kt = 0; kt < 4; ++kt) {
                    f32x4 v0 = *(const f32x4*)(ap + 32 * kt);
                    f32x4 v1 = *(const f32x4*)(ap + 32 * kt + 4);
                    S8 Ah, Al;
                    split_pair(v0[0], v0[1], Ah.u[0], Al.u[0]);
                    split_pair(v0[2], v0[3], Ah.u[1], Al.u[1]);
                    split_pair(v1[0], v1[1], Ah.u[2], Al.u[2]);
                    split_pair(v1[2], v1[3], Ah.u[3], Al.u[3]);
                    #pragma unroll
                    for (int nt = 0; nt < 6; ++nt) {
                        acc[nt] = MFMA16(Ah.s, Wh[nt][kt], acc[nt]);
                        acc[nt] = MFMA16(Al.s, Wh[nt][kt], acc[nt]);
                        acc[nt] = MFMA16(Ah.s, Wl[nt][kt], acc[nt]);
                    }
                }
                #pragma unroll
                for (int nt = 0; nt < 6; ++nt) {
                    const int col = 16 * (tb + nt) + l15;
                    #pragma unroll
                    for (int q = 0; q < 4; ++q)
                        Xb[bn][r][4 * l4 + q][col] = acc[nt][q] + b0c[nt];
                }
            }
        };

        produce(0);
        __syncthreads();
        for (int c = 0; c < NCHUNK; ++c) {
            if (c + 1 < NCHUNK) produce(c + 1);
            __syncthreads();
        }
    } else {
        // ======================= recurrence (row = wv) =======================
        // U columns as packed f16 k-pairs: uz2[p] = (U[2p][g], U[2p+1][g])
        u32 uz2[32], ur2[32], uh2c[32];
        #pragma unroll
        for (int p = 0; p < 32; ++p) {
            uz2[p]  = packf16(U[(size_t)(2 * p) * G3 + lane],
                              U[(size_t)(2 * p + 1) * G3 + lane]);
            ur2[p]  = packf16(U[(size_t)(2 * p) * G3 + 64 + lane],
                              U[(size_t)(2 * p + 1) * G3 + 64 + lane]);
            uh2c[p] = packf16(U[(size_t)(2 * p) * G3 + 128 + lane],
                              U[(size_t)(2 * p + 1) * G3 + 128 + lane]);
        }
        const float brz = bias[G3 + lane];
        const float brr = bias[G3 + 64 + lane];
        const float brh = bias[G3 + 128 + lane];
        const int odd = lane & 1;
        float h = 0.f;

        __syncthreads();

        for (int c = 0; c < NCHUNK; ++c) {
            const int buf = c & 1;
            for (int s = 0; s < CHUNK; ++s) {
                const float xz = Xb[buf][wv][s][lane];
                const float xr = Xb[buf][wv][s][64 + lane];
                const float xh = Xb[buf][wv][s][128 + lane];

                // ---- pack h pair: f16(own) + DPP quad-perm neighbor ----
                const u32 hu = f16bits(h);
                const u32 nb = (u32)__builtin_amdgcn_mov_dpp((int)hu, 0xB1, 0xF, 0xF, true);
                const u32 lo16 = odd ? nb : hu;
                const u32 hi16 = odd ? hu : nb;
                const u32 pk = lo16 | (hi16 << 16);

                float az = brz, ar = brr, ac = brh;
                #pragma unroll
                for (int p = 0; p < 32; ++p) {
                    const u32 hp = (u32)__builtin_amdgcn_readlane((int)pk, 2 * p);
                    az = dot2acc(hp, uz2[p],  az);
                    ar = dot2acc(hp, ur2[p],  ar);
                    ac = dot2acc(hp, uh2c[p], ac);
                }
                const float z  = sigmoidf_(xz + az);
                const float rg = sigmoidf_(xr + ar);
                const float hh = fmaxf(fmaf(rg, ac, xh), 0.f);
                h = fmaf(z, h - hh, hh);
            }
            __syncthreads();
        }

        // ---------------- epilogue: head + softmax (own row) ----------------
        hb[wv][lane] = h;
        WAVE_SYNC();

        float a = b1[lane];
        #pragma unroll 8
        for (int k = 0; k < UN; ++k)
            a = fmaf(hb[wv][k], W1[k * UN + lane], a);
        sc[wv][lane] = fmaxf(a, 0.f);
        WAVE_SYNC();

        if (lane < NCLS) {
            float acc = b2[lane];
            #pragma unroll 8
            for (int k = 0; k < UN; ++k)
                acc = fmaf(sc[wv][k], W2[k * NCLS + lane], acc);
            lg[wv][lane] = acc;
        }
        WAVE_SYNC();
        if (lane < NCLS) {
            float m = lg[wv][0];
            #pragma unroll
            for (int k = 1; k < NCLS; ++k) m = fmaxf(m, lg[wv][k]);
            float ss = 0.f;
            #pragma unroll
            for (int k = 0; k < NCLS; ++k) ss += __expf(lg[wv][k] - m);
            out[(r0 + wv) * NCLS + lane] = __expf(lg[wv][lane] - m) / ss;
        }
    }
}

extern "C" void kernel_launch(void* const* d_in, const int* in_sizes, int n_in,
                              void* d_out, int out_size, void* d_ws, size_t ws_size,
                              hipStream_t stream) {
    const float* inp  = (const float*)d_in[0];
    const float* W    = (const float*)d_in[1];
    const float* U    = (const float*)d_in[2];
    const float* bias = (const float*)d_in[3];
    const float* W1   = (const float*)d_in[4];
    const float* b1   = (const float*)d_in[5];
    const float* W2   = (const float*)d_in[6];
    const float* b2   = (const float*)d_in[7];
    float* out = (float*)d_out;

    gru_fused9<<<B_SZ / 2, 256, 0, stream>>>(inp, W, U, bias, W1, b1, W2, b2, out);
}

// Round 10
// 183.033 us; speedup vs baseline: 1.4797x; 1.2952x over previous
//
#include <hip/hip_runtime.h>

// Fused GRU (Keras reset_after=True, relu) for MI355X — round 10.
// r9 structure (237 µs); changes:
//  (1) rec wave PRELOADS the whole chunk's X gates (16 steps x 3) into
//      registers right after the chunk barrier (fully unrolled, static
//      indices) -> ZERO LDS ops inside the 16-step hot loop.
//  (2) each gate dot is split into 2 accumulation chains of 16 (6 chains
//      interleaved) -> half the dependent-chain latency.
// Block = 256 thr (4 waves) = 2 batch rows. Grid = 256, one pass.
//   Wave 0/1: recurrence row 0/1 (register-only steps, U f16-packed).
//   Wave 2/3: x-proj producers (bf16x3 MFMA, W frags resident, dbuf Xb).

#define B_SZ   512
#define T_SZ   512
#define F_SZ   128
#define UN     64
#define G3     192
#define CHUNK  16
#define NCHUNK (T_SZ / CHUNK)
#define NCLS   10
#define GP     196

using short8 = __attribute__((ext_vector_type(8))) short;
using f32x4  = __attribute__((ext_vector_type(4))) float;
using h2     = __attribute__((ext_vector_type(2))) __fp16;
typedef unsigned int u32;

union S8 { short8 s; u32 u[4]; };
union HU { h2 h; u32 u; };

__device__ __forceinline__ u32 permb(u32 a, u32 b, u32 sel) {
    return __builtin_amdgcn_perm(a, b, sel);
}
__device__ __forceinline__ unsigned short f2bf_rn(float f) {
    u32 u = __float_as_uint(f);
    u32 r = u + 0x7FFFu + ((u >> 16) & 1u);
    return (unsigned short)(r >> 16);
}
__device__ __forceinline__ float bf2f(unsigned short s) {
    return __uint_as_float(((u32)s) << 16);
}
__device__ __forceinline__ float sigmoidf_(float x) {
    return 1.0f / (1.0f + __expf(-x));
}
__device__ __forceinline__ void split_pair(float f0, float f1, u32 &hi, u32 &lo) {
    u32 u0 = __float_as_uint(f0) & 0xffff0000u;
    u32 u1 = __float_as_uint(f1) & 0xffff0000u;
    float l0 = f0 - __uint_as_float(u0);
    float l1 = f1 - __uint_as_float(u1);
    hi = permb(u1, u0, 0x07060302u);
    lo = permb(__float_as_uint(l1), __float_as_uint(l0), 0x07060302u);
}
__device__ __forceinline__ u32 f16bits(float f) {
    __fp16 x = (__fp16)f;
    return (u32)__builtin_bit_cast(unsigned short, x);
}
__device__ __forceinline__ u32 packf16(float f0, float f1) {
    return f16bits(f0) | (f16bits(f1) << 16);
}
__device__ __forceinline__ float dot2acc(u32 hp, u32 up, float acc) {
#if __has_builtin(__builtin_amdgcn_fdot2)
    HU a, b; a.u = hp; b.u = up;
    return __builtin_amdgcn_fdot2(a.h, b.h, acc, false);
#else
    HU a, b; a.u = hp; b.u = up;
    acc = fmaf((float)a.h[0], (float)b.h[0], acc);
    return fmaf((float)a.h[1], (float)b.h[1], acc);
#endif
}
#define WAVE_SYNC() asm volatile("s_waitcnt lgkmcnt(0)" ::: "memory")
#define MFMA16(A, B, C) __builtin_amdgcn_mfma_f32_16x16x32_bf16((A), (B), (C), 0, 0, 0)

__global__ __launch_bounds__(256, 1)
void gru_fused10(const float* __restrict__ inp,   // [512,512,128]
                 const float* __restrict__ W,     // [128,192]
                 const float* __restrict__ U,     // [64,192]
                 const float* __restrict__ bias,  // [2,192]
                 const float* __restrict__ W1,    // [64,64]
                 const float* __restrict__ b1,    // [64]
                 const float* __restrict__ W2,    // [64,10]
                 const float* __restrict__ b2,    // [10]
                 float* __restrict__ out)         // [512,10]
{
    const int tid  = threadIdx.x;
    const int wv   = tid >> 6;
    const int lane = tid & 63;
    const int l15  = lane & 15;
    const int l4   = lane >> 4;
    const int r0   = blockIdx.x * 2;

    __shared__ __align__(16) float Xb[2][2][CHUNK][GP];
    __shared__ float hb[2][UN];
    __shared__ float sc[2][UN];
    __shared__ float lg[2][NCLS];

    if (wv >= 2) {
        // ======================= producers (r7-identical) =======================
        const int tb = 6 * (wv - 2);
        short8 Wh[6][4], Wl[6][4];
        float  b0c[6];
        #pragma unroll
        for (int nt = 0; nt < 6; ++nt) {
            const int col = 16 * (tb + nt) + l15;
            b0c[nt] = bias[col];
            #pragma unroll
            for (int kt = 0; kt < 4; ++kt) {
                #pragma unroll
                for (int e = 0; e < 8; ++e) {
                    float w = W[(size_t)(32 * kt + 8 * l4 + e) * G3 + col];
                    unsigned short hi = f2bf_rn(w);
                    Wh[nt][kt][e] = (short)hi;
                    Wl[nt][kt][e] = (short)f2bf_rn(w - bf2f(hi));
                }
            }
        }

        auto produce = [&](int cn) {
            const int bn = cn & 1;
            #pragma unroll
            for (int r = 0; r < 2; ++r) {
                const float* ap = inp + (size_t)(r0 + r) * T_SZ * F_SZ
                                + (size_t)(cn * CHUNK + l15) * F_SZ + 8 * l4;
                f32x4 acc[6];
                #pragma unroll
                for (int nt = 0; nt < 6; ++nt) acc[nt] = (f32x4){0.f, 0.f, 0.f, 0.f};
                #pragma unroll
                for (int kt = 0; kt < 4; ++kt) {
                    f32x4 v0 = *(const f32x4*)(ap + 32 * kt);
                    f32x4 v1 = *(const f32x4*)(ap + 32 * kt + 4);
                    S8 Ah, Al;
                    split_pair(v0[0], v0[1], Ah.u[0], Al.u[0]);
                    split_pair(v0[2], v0[3], Ah.u[1], Al.u[1]);
                    split_pair(v1[0], v1[1], Ah.u[2], Al.u[2]);
                    split_pair(v1[2], v1[3], Ah.u[3], Al.u[3]);
                    #pragma unroll
                    for (int nt = 0; nt < 6; ++nt) {
                        acc[nt] = MFMA16(Ah.s, Wh[nt][kt], acc[nt]);
                        acc[nt] = MFMA16(Al.s, Wh[nt][kt], acc[nt]);
                        acc[nt] = MFMA16(Ah.s, Wl[nt][kt], acc[nt]);
                    }
                }
                #pragma unroll
                for (int nt = 0; nt < 6; ++nt) {
                    const int col = 16 * (tb + nt) + l15;
                    #pragma unroll
                    for (int q = 0; q < 4; ++q)
                        Xb[bn][r][4 * l4 + q][col] = acc[nt][q] + b0c[nt];
                }
            }
        };

        produce(0);
        __syncthreads();
        for (int c = 0; c < NCHUNK; ++c) {
            if (c + 1 < NCHUNK) produce(c + 1);
            __syncthreads();
        }
    } else {
        // ======================= recurrence (row = wv) =======================
        u32 uz2[32], ur2[32], uh2c[32];
        #pragma unroll
        for (int p = 0; p < 32; ++p) {
            uz2[p]  = packf16(U[(size_t)(2 * p) * G3 + lane],
                              U[(size_t)(2 * p + 1) * G3 + lane]);
            ur2[p]  = packf16(U[(size_t)(2 * p) * G3 + 64 + lane],
                              U[(size_t)(2 * p + 1) * G3 + 64 + lane]);
            uh2c[p] = packf16(U[(size_t)(2 * p) * G3 + 128 + lane],
                              U[(size_t)(2 * p + 1) * G3 + 128 + lane]);
        }
        const float brz = bias[G3 + lane];
        const float brr = bias[G3 + 64 + lane];
        const float brh = bias[G3 + 128 + lane];
        const int odd = lane & 1;
        float h = 0.f;

        __syncthreads();

        for (int c = 0; c < NCHUNK; ++c) {
            const int buf = c & 1;

            // ---- chunk preload: all 48 gate values into registers ----
            float xzv[CHUNK], xrv[CHUNK], xhv[CHUNK];
            #pragma unroll
            for (int s = 0; s < CHUNK; ++s) {
                xzv[s] = Xb[buf][wv][s][lane];
                xrv[s] = Xb[buf][wv][s][64 + lane];
                xhv[s] = Xb[buf][wv][s][128 + lane];
            }

            // ---- 16 register-only steps ----
            #pragma unroll
            for (int s = 0; s < CHUNK; ++s) {
                // pack h pair: f16(own) + DPP quad-perm neighbor
                const u32 hu = f16bits(h);
                const u32 nb = (u32)__builtin_amdgcn_mov_dpp((int)hu, 0xB1, 0xF, 0xF, true);
                const u32 lo16 = odd ? nb : hu;
                const u32 hi16 = odd ? hu : nb;
                const u32 pk = lo16 | (hi16 << 16);

                // 6 interleaved chains of 16
                float az0 = brz, ar0 = brr, ac0 = brh;
                float az1 = 0.f, ar1 = 0.f, ac1 = 0.f;
                #pragma unroll
                for (int p = 0; p < 16; ++p) {
                    const u32 hpa = (u32)__builtin_amdgcn_readlane((int)pk, 2 * p);
                    const u32 hpb = (u32)__builtin_amdgcn_readlane((int)pk, 2 * p + 32);
                    az0 = dot2acc(hpa, uz2[p],       az0);
                    ar0 = dot2acc(hpa, ur2[p],       ar0);
                    ac0 = dot2acc(hpa, uh2c[p],      ac0);
                    az1 = dot2acc(hpb, uz2[p + 16],  az1);
                    ar1 = dot2acc(hpb, ur2[p + 16],  ar1);
                    ac1 = dot2acc(hpb, uh2c[p + 16], ac1);
                }
                const float z  = sigmoidf_(xzv[s] + az0 + az1);
                const float rg = sigmoidf_(xrv[s] + ar0 + ar1);
                const float hh = fmaxf(fmaf(rg, ac0 + ac1, xhv[s]), 0.f);
                h = fmaf(z, h - hh, hh);
            }
            __syncthreads();
        }

        // ---------------- epilogue: head + softmax (own row) ----------------
        hb[wv][lane] = h;
        WAVE_SYNC();

        float a = b1[lane];
        #pragma unroll 8
        for (int k = 0; k < UN; ++k)
            a = fmaf(hb[wv][k], W1[k * UN + lane], a);
        sc[wv][lane] = fmaxf(a, 0.f);
        WAVE_SYNC();

        if (lane < NCLS) {
            float acc = b2[lane];
            #pragma unroll 8
            for (int k = 0; k < UN; ++k)
                acc = fmaf(sc[wv][k], W2[k * NCLS + lane], acc);
            lg[wv][lane] = acc;
        }
        WAVE_SYNC();
        if (lane < NCLS) {
            float m = lg[wv][0];
            #pragma unroll
            for (int k = 1; k < NCLS; ++k) m = fmaxf(m, lg[wv][k]);
            float ss = 0.f;
            #pragma unroll
            for (int k = 0; k < NCLS; ++k) ss += __expf(lg[wv][k] - m);
            out[(r0 + wv) * NCLS + lane] = __expf(lg[wv][lane] - m) / ss;
        }
    }
}

extern "C" void kernel_launch(void* const* d_in, const int* in_sizes, int n_in,
                              void* d_out, int out_size, void* d_ws, size_t ws_size,
                              hipStream_t stream) {
    const float* inp  = (const float*)d_in[0];
    const float* W    = (const float*)d_in[1];
    const float* U    = (const float*)d_in[2];
    const float* bias = (const float*)d_in[3];
    const float* W1   = (const float*)d_in[4];
    const float* b1   = (const float*)d_in[5];
    const float* W2   = (const float*)d_in[6];
    const float* b2   = (const float*)d_in[7];
    float* out = (float*)d_out;

    gru_fused10<<<B_SZ / 2, 256, 0, stream>>>(inp, W, U, bias, W1, b1, W2, b2, out);
}